// Round 7
// baseline (223.174 us; speedup 1.0000x reference)
//
#include <hip/hip_runtime.h>

typedef unsigned int uint;

#define NPTS 4096
#define BLK  256
#define QPB  8            // queries per block
#define TPQ  32           // threads per query
#define KNN  32
#define KSUP 8
#define TILE 512          // points staged per LDS tile
#define NTILE (NPTS/TILE) // 8
#define MAXCQ 192         // per-query fast-path candidate cap
#define FBCAP (QPB*MAXCQ) // 1536 flattened slots for fallback
#define NBIN 1024
#define LINSCALE 16.0f

// ---------------- Pass 0: pack xyz -> float4 {x,y,z,|x|^2} ----------------
__global__ __launch_bounds__(64) void pack_kernel(
        const float* __restrict__ xyz, float4* __restrict__ pts4, int total)
{
    int i = blockIdx.x * 64 + threadIdx.x;
    if (i < total) {
        float x = xyz[i*3+0], y = xyz[i*3+1], z = xyz[i*3+2];
        pts4[i] = make_float4(x, y, z, x*x + y*y + z*z);
    }
}

__device__ __forceinline__ uint fkey(float d) {
    uint u = __float_as_uint(d);
    return u ^ ((u & 0x80000000u) ? 0xFFFFFFFFu : 0x80000000u);
}
__device__ __forceinline__ uint linbin(float d) {
    return (uint)fmaxf(fminf(d * LINSCALE, 1023.0f), 0.0f);
}

// block: parallel crossing-bin find over 1024-bin hist (lanes 0..63)
__device__ __forceinline__ void find_cross(const uint* hist, uint* s_bin, int tid) {
    if (tid < 64) {
        const uint4* h4 = (const uint4*)hist;
        uint4 h0 = h4[tid*4+0], h1 = h4[tid*4+1], h2 = h4[tid*4+2], h3 = h4[tid*4+3];
        uint s = h0.x+h0.y+h0.z+h0.w + h1.x+h1.y+h1.z+h1.w
               + h2.x+h2.y+h2.z+h2.w + h3.x+h3.y+h3.z+h3.w;
        uint t = s;
        #pragma unroll
        for (int off = 1; off < 64; off <<= 1) {
            uint u = __shfl_up(t, off, 64);
            if (tid >= off) t += u;
        }
        uint ex = t - s;
        if (ex < KNN && ex + s >= KNN) {
            uint cum = ex, binoff = 0;
            cum += h0.x; binoff += (cum < KNN); cum += h0.y; binoff += (cum < KNN);
            cum += h0.z; binoff += (cum < KNN); cum += h0.w; binoff += (cum < KNN);
            cum += h1.x; binoff += (cum < KNN); cum += h1.y; binoff += (cum < KNN);
            cum += h1.z; binoff += (cum < KNN); cum += h1.w; binoff += (cum < KNN);
            cum += h2.x; binoff += (cum < KNN); cum += h2.y; binoff += (cum < KNN);
            cum += h2.z; binoff += (cum < KNN); cum += h2.w; binoff += (cum < KNN);
            cum += h3.x; binoff += (cum < KNN); cum += h3.y; binoff += (cum < KNN);
            cum += h3.z; binoff += (cum < KNN); cum += h3.w; binoff += (cum < KNN);
            *s_bin = tid * 16u + binoff;
        }
    }
}

// ---------------- Pass 1: exact kNN + covariance, 8 queries/block ----------------
__global__ __launch_bounds__(256) void knn_cov_kernel(
        const float4* __restrict__ pts4,  // [B][N] {x,y,z,sq}
        float* __restrict__ covS,         // [B*N][12]: cov6, S3, pad
        int*   __restrict__ idx8)         // [B*N][8]
{
    const int bid = blockIdx.x;                // b*(N/QPB) + qg
    const int b   = bid / (NPTS / QPB);
    const int qg  = bid % (NPTS / QPB);
    const int tid = threadIdx.x;
    const int g   = tid >> 5;                  // query slot 0..7
    const int t   = tid & 31;                  // lane within query group
    const int n   = qg * QPB + g;              // query index within batch
    const int pid = b * NPTS + n;
    const float4* P = pts4 + (size_t)b * NPTS;

    __shared__ float4 stage[TILE];             // 8 KB (reused as hist in fallback)
    __shared__ uint ckey[QPB][MAXCQ];          // 6 KB
    __shared__ int  cidx[QPB][MAXCQ];          // 6 KB
    __shared__ int  sel[QPB][KNN];             // 1 KB
    __shared__ uint ccnt[QPB];
    __shared__ uint s_flag;
    __shared__ uint s_bin, s_cnt2;

    const float4 q = P[n];
    const float qx = q.x, qy = q.y, qz = q.z, sqn = q.w;
    // analytic 32-NN radius bound for N(0,1)^3, safety 1.3 on radius^2 basis
    const float t0 = 0.1606f * __expf(sqn * (1.0f / 3.0f));

    if (tid < QPB) ccnt[tid] = 0;
    if (tid == 0) s_flag = 0;
    __syncthreads();

    // ---- tiled scan: stage 512 points in LDS, 8 queries share them ----
    for (int tile = 0; tile < NTILE; ++tile) {
        const int base = tile * TILE;
        stage[tid]       = P[base + tid];
        stage[tid + BLK] = P[base + tid + BLK];
        __syncthreads();
        #pragma unroll 4
        for (int k = 0; k < TILE / TPQ; ++k) {   // 16 iters
            const int j = t + k * TPQ;
            float4 p = stage[j];
            float d = sqn + p.w - 2.0f * (qx * p.x + qy * p.y + qz * p.z);
            if (d < t0) {
                uint pos = atomicAdd(&ccnt[g], 1u);
                if (pos < MAXCQ) { ckey[g][pos] = fkey(d); cidx[g][pos] = base + j; }
            }
        }
        __syncthreads();
    }

    if (t == 0) {
        uint c = ccnt[g];
        if (c < KNN || c > MAXCQ) atomicOr(&s_flag, 1u << g);
    }
    __syncthreads();
    const uint flags = s_flag;

    // ---- fast-path rank selection (key asc, index asc) -> sel[g][0..31] ----
    if (!((flags >> g) & 1u)) {
        const int M = (int)ccnt[g];
        for (int i = t; i < M; i += TPQ) {
            uint uk = ckey[g][i]; int ui = cidx[g][i];
            int r = 0;
            for (int j = 0; j < M; ++j) {
                uint vk = ckey[g][j];
                r += (vk < uk || (vk == uk && cidx[g][j] < ui)) ? 1 : 0;
            }
            if (r < KNN) sel[g][r] = ui;
        }
    }
    __syncthreads();

    // ---- exact fallback, serial per flagged query, whole block ----
    if (flags) {
        uint* hist   = (uint*)stage;           // 4 KB of the 8 KB stage
        uint* fkeys  = &ckey[0][0];            // flattened 1536 slots
        int*  fidx   = &cidx[0][0];
        for (int g2 = 0; g2 < QPB; ++g2) {
            if (!((flags >> g2) & 1u)) continue;
            const int n2 = qg * QPB + g2;
            const float4 q2 = P[n2];
            const float q2x = q2.x, q2y = q2.y, q2z = q2.z, sq2 = q2.w;

            for (int i = tid; i < NBIN; i += BLK) hist[i] = 0;
            if (tid == 0) s_cnt2 = 0;
            __syncthreads();
            for (int m = tid; m < NPTS; m += BLK) {
                float4 p = P[m];
                float d = sq2 + p.w - 2.0f * (q2x * p.x + q2y * p.y + q2z * p.z);
                atomicAdd(&hist[linbin(d)], 1u);
            }
            __syncthreads();
            find_cross(hist, &s_bin, tid);
            __syncthreads();
            const uint bmax = s_bin;
            for (int m = tid; m < NPTS; m += BLK) {
                float4 p = P[m];
                float d = sq2 + p.w - 2.0f * (q2x * p.x + q2y * p.y + q2z * p.z);
                if (linbin(d) <= bmax) {
                    uint pos = atomicAdd(&s_cnt2, 1u);
                    if (pos < FBCAP) { fkeys[pos] = fkey(d); fidx[pos] = m; }
                }
            }
            __syncthreads();
            const uint cnt2 = s_cnt2;
            if (cnt2 <= FBCAP) {
                const int M2 = (int)cnt2;
                for (int i = tid; i < M2; i += BLK) {
                    uint uk = fkeys[i]; int ui = fidx[i];
                    int r = 0;
                    for (int j = 0; j < M2; ++j) {
                        uint vk = fkeys[j];
                        r += (vk < uk || (vk == uk && fidx[j] < ui)) ? 1 : 0;
                    }
                    if (r < KNN) sel[g2][r] = ui;
                }
            } else {
                // last-resort brute exact rank (unreachable on sane data)
                for (int m = tid; m < NPTS; m += BLK) {
                    float4 pm = P[m];
                    float dm = sq2 + pm.w - 2.0f * (q2x * pm.x + q2y * pm.y + q2z * pm.z);
                    uint km = fkey(dm);
                    int r = 0;
                    for (int j = 0; j < NPTS; ++j) {
                        float4 pj = P[j];
                        float dj = sq2 + pj.w - 2.0f * (q2x * pj.x + q2y * pj.y + q2z * pj.z);
                        uint kj = fkey(dj);
                        r += (kj < km || (kj == km && j < m)) ? 1 : 0;
                    }
                    if (r < KNN) sel[g2][r] = m;
                }
            }
            __syncthreads();
        }
    }
    __syncthreads();

    // ---- per-group covariance: 32 threads, 1 neighbor each ----
    {
        int jn = sel[g][t];
        float4 pj = P[jn];
        float p0 = pj.x, p1 = pj.y, p2 = pj.z;

        float s0 = p0, s1 = p1, s2 = p2;
        #pragma unroll
        for (int ml = 1; ml < 32; ml <<= 1) {
            s0 += __shfl_xor(s0, ml, 32);
            s1 += __shfl_xor(s1, ml, 32);
            s2 += __shfl_xor(s2, ml, 32);
        }
        const float c0 = s0 * (1.0f/32.0f), c1 = s1 * (1.0f/32.0f), c2 = s2 * (1.0f/32.0f);
        const float X0 = p0 - c0, X1 = p1 - c1, X2 = p2 - c2;
        float xx = X0*X0, xy = X0*X1, xz = X0*X2, yy = X1*X1, yz = X1*X2, zz = X2*X2;
        #pragma unroll
        for (int ml = 1; ml < 32; ml <<= 1) {
            xx += __shfl_xor(xx, ml, 32);
            xy += __shfl_xor(xy, ml, 32);
            xz += __shfl_xor(xz, ml, 32);
            yy += __shfl_xor(yy, ml, 32);
            yz += __shfl_xor(yz, ml, 32);
            zz += __shfl_xor(zz, ml, 32);
        }
        if (t == 0) {
            float4* o = (float4*)(covS + (size_t)pid * 12);
            o[0] = make_float4(xx, xy, xz, yy);
            o[1] = make_float4(yz, zz, s0 - 32.0f*qx, s1 - 32.0f*qy);
            o[2] = make_float4(s2 - 32.0f*qz, 0.0f, 0.0f, 0.0f);
        }
        if (t < KSUP) idx8[(size_t)pid*KSUP + t] = sel[g][t];
    }
}

// ---------------- Pass 1b: per-thread 3x3 eigensolve -> oriented normal ----------------
__global__ __launch_bounds__(64) void eig_kernel(
        const float* __restrict__ covS, float* __restrict__ normals, int total)
{
    const int pid = blockIdx.x * 64 + threadIdx.x;
    if (pid >= total) return;
    const float4* c4 = (const float4*)(covS + (size_t)pid * 12);
    const float4 a = c4[0], bb = c4[1], cc = c4[2];

    double A00 = a.x, A01 = a.y, A02 = a.z, A11 = a.w, A12 = bb.x, A22 = bb.y;
    const float S0 = bb.z, S1 = bb.w, S2 = cc.x;
    double V00=1, V01=0, V02=0, V10=0, V11=1, V12=0, V20=0, V21=0, V22=1;

    #pragma unroll
    for (int sweep = 0; sweep < 5; ++sweep) {
        {
            double apq = A01;
            if (fabs(apq) > 1e-300) {
                double th = (A11 - A00) / (2.0*apq);
                double t  = (th >= 0.0 ? 1.0 : -1.0) / (fabs(th) + sqrt(th*th + 1.0));
                double c  = 1.0/sqrt(t*t + 1.0), s = t*c;
                double a00 = c*c*A00 - 2.0*s*c*A01 + s*s*A11;
                double a11 = s*s*A00 + 2.0*s*c*A01 + c*c*A11;
                double a02 = c*A02 - s*A12;
                double a12 = s*A02 + c*A12;
                A00 = a00; A11 = a11; A01 = 0.0; A02 = a02; A12 = a12;
                double v0, v1;
                v0 = V00; v1 = V01; V00 = c*v0 - s*v1; V01 = s*v0 + c*v1;
                v0 = V10; v1 = V11; V10 = c*v0 - s*v1; V11 = s*v0 + c*v1;
                v0 = V20; v1 = V21; V20 = c*v0 - s*v1; V21 = s*v0 + c*v1;
            }
        }
        {
            double apq = A02;
            if (fabs(apq) > 1e-300) {
                double th = (A22 - A00) / (2.0*apq);
                double t  = (th >= 0.0 ? 1.0 : -1.0) / (fabs(th) + sqrt(th*th + 1.0));
                double c  = 1.0/sqrt(t*t + 1.0), s = t*c;
                double a00 = c*c*A00 - 2.0*s*c*A02 + s*s*A22;
                double a22 = s*s*A00 + 2.0*s*c*A02 + c*c*A22;
                double a01 = c*A01 - s*A12;
                double a12 = s*A01 + c*A12;
                A00 = a00; A22 = a22; A02 = 0.0; A01 = a01; A12 = a12;
                double v0, v1;
                v0 = V00; v1 = V02; V00 = c*v0 - s*v1; V02 = s*v0 + c*v1;
                v0 = V10; v1 = V12; V10 = c*v0 - s*v1; V12 = s*v0 + c*v1;
                v0 = V20; v1 = V22; V20 = c*v0 - s*v1; V22 = s*v0 + c*v1;
            }
        }
        {
            double apq = A12;
            if (fabs(apq) > 1e-300) {
                double th = (A22 - A11) / (2.0*apq);
                double t  = (th >= 0.0 ? 1.0 : -1.0) / (fabs(th) + sqrt(th*th + 1.0));
                double c  = 1.0/sqrt(t*t + 1.0), s = t*c;
                double a11 = c*c*A11 - 2.0*s*c*A12 + s*s*A22;
                double a22 = s*s*A11 + 2.0*s*c*A12 + c*c*A22;
                double a01 = c*A01 - s*A02;
                double a02 = s*A01 + c*A02;
                A11 = a11; A22 = a22; A12 = 0.0; A01 = a01; A02 = a02;
                double v0, v1;
                v0 = V01; v1 = V02; V01 = c*v0 - s*v1; V02 = s*v0 + c*v1;
                v0 = V11; v1 = V12; V11 = c*v0 - s*v1; V12 = s*v0 + c*v1;
                v0 = V21; v1 = V22; V21 = c*v0 - s*v1; V22 = s*v0 + c*v1;
            }
        }
    }

    double e0 = A00, e1 = A11, e2 = A22;
    double v0, v1, v2;
    if (e0 <= e1 && e0 <= e2)      { v0 = V00; v1 = V10; v2 = V20; }
    else if (e1 <= e0 && e1 <= e2) { v0 = V01; v1 = V11; v2 = V21; }
    else                           { v0 = V02; v1 = V12; v2 = V22; }
    double nrm = sqrt(v0*v0 + v1*v1 + v2*v2);
    if (nrm > 0.0) { v0 /= nrm; v1 /= nrm; v2 /= nrm; }

    float f0 = (float)v0, f1 = (float)v1, f2 = (float)v2;
    float proj = f0*S0 + f1*S1 + f2*S2;
    if (proj < 0.0f) { f0 = -f0; f1 = -f1; f2 = -f2; }
    normals[(size_t)pid*3+0] = f0;
    normals[(size_t)pid*3+1] = f1;
    normals[(size_t)pid*3+2] = f2;
}

// ---------------- Pass 2: penalty std + batch mean ----------------
__global__ __launch_bounds__(64) void penalty_kernel(
        const float* __restrict__ normals,
        const int*   __restrict__ idx8,
        float*       __restrict__ out)
{
    const int pid = blockIdx.x * 64 + threadIdx.x;    // < B*N
    const int b   = pid >> 12;
    const int* my = idx8 + (size_t)pid * KSUP;
    const float* nb_base = normals + (size_t)b * NPTS * 3;

    const int i0 = my[0];
    const float a0 = nb_base[i0*3+0], a1 = nb_base[i0*3+1], a2 = nb_base[i0*3+2];
    const float na = fmaxf(sqrtf(a0*a0 + a1*a1 + a2*a2), 1e-6f);

    float p[KSUP];
    float sum = 0.0f;
    #pragma unroll
    for (int k = 0; k < KSUP; ++k) {
        int ik = my[k];
        float b0 = nb_base[ik*3+0], b1 = nb_base[ik*3+1], b2 = nb_base[ik*3+2];
        float nbn = fmaxf(sqrtf(b0*b0 + b1*b1 + b2*b2), 1e-6f);
        float cosv = (a0*b0 + a1*b1 + a2*b2) / (na * nbn);
        p[k] = 1.0f - cosv;
        sum += p[k];
    }
    const float mean = sum * (1.0f / 8.0f);
    float var = 0.0f;
    #pragma unroll
    for (int k = 0; k < KSUP; ++k) { float dv = p[k] - mean; var += dv * dv; }
    float v = sqrtf(var * (1.0f / 7.0f)) * (1.0f / 4096.0f);

    #pragma unroll
    for (int ml = 1; ml < 64; ml <<= 1) v += __shfl_xor(v, ml, 64);
    if (threadIdx.x == 0) atomicAdd(&out[b], v);
}

extern "C" void kernel_launch(void* const* d_in, const int* in_sizes, int n_in,
                              void* d_out, int out_size, void* d_ws, size_t ws_size,
                              hipStream_t stream) {
    const float* xyz = (const float*)d_in[0];
    float* out = (float*)d_out;

    const int B = in_sizes[0] / (NPTS * 3);   // 4
    const int total = B * NPTS;

    char* ws = (char*)d_ws;
    float4* pts4   = (float4*)ws;                       ws += (size_t)total * sizeof(float4);
    float*  covS   = (float*)ws;                        ws += (size_t)total * 12 * sizeof(float);
    float*  normals= (float*)ws;                        ws += (size_t)total * 3 * sizeof(float);
    int*    idx8   = (int*)ws;

    hipMemsetAsync(d_out, 0, (size_t)out_size * sizeof(float), stream);

    hipLaunchKernelGGL(pack_kernel, dim3((total + 63) / 64), dim3(64), 0, stream,
                       xyz, pts4, total);
    hipLaunchKernelGGL(knn_cov_kernel, dim3(total / QPB), dim3(BLK), 0, stream,
                       pts4, covS, idx8);
    hipLaunchKernelGGL(eig_kernel, dim3((total + 63) / 64), dim3(64), 0, stream,
                       covS, normals, total);
    hipLaunchKernelGGL(penalty_kernel, dim3(total / 64), dim3(64), 0, stream,
                       normals, idx8, out);
}

// Round 8
// 175.421 us; speedup vs baseline: 1.2722x; 1.2722x over previous
//
#include <hip/hip_runtime.h>

typedef unsigned int uint;
typedef unsigned long long u64;

#define NPTS 4096
#define KNN  32
#define KSUP 8
#define QPB  4            // queries (waves) per block
#define MAXCQ 192         // per-query candidate cap

// ---------------- Pass 0: pack xyz -> float4 {x,y,z,|x|^2}; zero d_out ----------------
__global__ __launch_bounds__(64) void pack_kernel(
        const float* __restrict__ xyz, float4* __restrict__ pts4, int total,
        float* __restrict__ out, int nout)
{
    int i = blockIdx.x * 64 + threadIdx.x;
    if (i < total) {
        float x = xyz[i*3+0], y = xyz[i*3+1], z = xyz[i*3+2];
        pts4[i] = make_float4(x, y, z, x*x + y*y + z*z);
    }
    if (blockIdx.x == 0 && threadIdx.x < nout) out[threadIdx.x] = 0.0f;
}

__device__ __forceinline__ uint fkey(float d) {
    uint u = __float_as_uint(d);
    return u ^ ((u & 0x80000000u) ? 0xFFFFFFFFu : 0x80000000u);
}

// ---------------- Pass 1: exact kNN + covariance, 1 wave per query ----------------
__global__ __launch_bounds__(256) void knn_cov_kernel(
        const float4* __restrict__ pts4,  // [B][N] {x,y,z,sq}
        float* __restrict__ covS,         // [B*N][12]: cov6, S3, pad
        int*   __restrict__ idx8)         // [B*N][8]
{
    const int tid  = threadIdx.x;
    const int g    = tid >> 6;                 // wave slot 0..3
    const int lane = tid & 63;
    const int bid  = blockIdx.x;               // b*(N/QPB) + qg
    const int b    = bid / (NPTS / QPB);
    const int n    = (bid % (NPTS / QPB)) * QPB + g;
    const int pid  = b * NPTS + n;
    const float4* P = pts4 + (size_t)b * NPTS;

    __shared__ u64 cand[QPB][MAXCQ];           // 6 KB
    __shared__ int sel[QPB][KNN];              // 0.5 KB

    const float4 q = P[n];
    const float qx = q.x, qy = q.y, qz = q.z, sqn = q.w;
    // analytic 32-NN radius bound for N(0,1)^3 (E[cnt]~70 at center density)
    float t = 0.1606f * __expf(sqn * (1.0f / 3.0f));

    // ---- collect candidates: ballot compaction, adaptive threshold ----
    uint cnt = 0;
    bool ok = false;
    for (int attempt = 0; attempt < 8 && !ok; ++attempt) {
        cnt = 0;
        #pragma unroll 4
        for (int k0 = 0; k0 < NPTS; k0 += 64) {
            const int k = k0 + lane;
            float4 p = P[k];
            float d = sqn + p.w - 2.0f * (qx * p.x + qy * p.y + qz * p.z);
            bool pred = d < t;
            u64 mask = __ballot(pred);
            if (pred) {
                uint pos = cnt + __builtin_amdgcn_mbcnt_hi((uint)(mask >> 32),
                            __builtin_amdgcn_mbcnt_lo((uint)mask, 0u));
                if (pos < MAXCQ) cand[g][pos] = ((u64)fkey(d) << 12) | (uint)k;
            }
            cnt += (uint)__popcll(mask);
        }
        if (cnt >= KNN && cnt <= MAXCQ) ok = true;
        else t = (cnt < KNN) ? t * 2.2f : t * 0.5f;
    }

    if (ok) {
        // ---- exact stable rank selection on packed (key,idx) u64 ----
        const int M = (int)cnt;
        const int rounds = (M + 63) >> 6;
        for (int rr = 0; rr < rounds; ++rr) {
            const int i = rr * 64 + lane;
            u64 my = (i < M) ? cand[g][i] : ~0ull;
            int r = 0;
            for (int j = 0; j < M; ++j) r += (cand[g][j] < my) ? 1 : 0;
            if (i < M && r < KNN) sel[g][r] = (int)(my & 0xFFFull);
        }
    } else {
        // ---- guaranteed-exact terminal: 32 wave-parallel min-extractions ----
        u64 last = 0;
        for (int r = 0; r < KNN; ++r) {
            u64 best = ~0ull;
            for (int k0 = 0; k0 < NPTS; k0 += 64) {
                const int k = k0 + lane;
                float4 p = P[k];
                float d = sqn + p.w - 2.0f * (qx * p.x + qy * p.y + qz * p.z);
                u64 pk = ((u64)fkey(d) << 12) | (uint)k;
                if (pk > last && pk < best) best = pk;
            }
            #pragma unroll
            for (int off = 32; off; off >>= 1) {
                u64 o = __shfl_xor(best, off, 64);
                best = (o < best) ? o : best;
            }
            if (lane == 0) sel[g][r] = (int)(best & 0xFFFull);
            last = best;
        }
    }
    __syncthreads();   // sel[] visibility for cov/idx8 reads below

    // ---- covariance: lanes 0..31 of each wave, 1 neighbor each ----
    if (lane < 32) {
        const int jn = sel[g][lane];
        float4 pj = P[jn];
        float p0 = pj.x, p1 = pj.y, p2 = pj.z;

        float s0 = p0, s1 = p1, s2 = p2;
        #pragma unroll
        for (int ml = 1; ml < 32; ml <<= 1) {
            s0 += __shfl_xor(s0, ml, 32);
            s1 += __shfl_xor(s1, ml, 32);
            s2 += __shfl_xor(s2, ml, 32);
        }
        const float c0 = s0 * (1.0f/32.0f), c1 = s1 * (1.0f/32.0f), c2 = s2 * (1.0f/32.0f);
        const float X0 = p0 - c0, X1 = p1 - c1, X2 = p2 - c2;
        float xx = X0*X0, xy = X0*X1, xz = X0*X2, yy = X1*X1, yz = X1*X2, zz = X2*X2;
        #pragma unroll
        for (int ml = 1; ml < 32; ml <<= 1) {
            xx += __shfl_xor(xx, ml, 32);
            xy += __shfl_xor(xy, ml, 32);
            xz += __shfl_xor(xz, ml, 32);
            yy += __shfl_xor(yy, ml, 32);
            yz += __shfl_xor(yz, ml, 32);
            zz += __shfl_xor(zz, ml, 32);
        }
        if (lane == 0) {
            float4* o = (float4*)(covS + (size_t)pid * 12);
            o[0] = make_float4(xx, xy, xz, yy);
            o[1] = make_float4(yz, zz, s0 - 32.0f*qx, s1 - 32.0f*qy);
            o[2] = make_float4(s2 - 32.0f*qz, 0.0f, 0.0f, 0.0f);
        }
    }
    if (lane < KSUP) idx8[(size_t)pid*KSUP + lane] = sel[g][lane];
}

// ---------------- Pass 1b: per-thread 3x3 eigensolve -> oriented normal ----------------
__global__ __launch_bounds__(64) void eig_kernel(
        const float* __restrict__ covS, float* __restrict__ normals, int total)
{
    const int pid = blockIdx.x * 64 + threadIdx.x;
    if (pid >= total) return;
    const float4* c4 = (const float4*)(covS + (size_t)pid * 12);
    const float4 a = c4[0], bb = c4[1], cc = c4[2];

    double A00 = a.x, A01 = a.y, A02 = a.z, A11 = a.w, A12 = bb.x, A22 = bb.y;
    const float S0 = bb.z, S1 = bb.w, S2 = cc.x;
    double V00=1, V01=0, V02=0, V10=0, V11=1, V12=0, V20=0, V21=0, V22=1;

    #pragma unroll
    for (int sweep = 0; sweep < 5; ++sweep) {
        {
            double apq = A01;
            if (fabs(apq) > 1e-300) {
                double th = (A11 - A00) / (2.0*apq);
                double t  = (th >= 0.0 ? 1.0 : -1.0) / (fabs(th) + sqrt(th*th + 1.0));
                double c  = 1.0/sqrt(t*t + 1.0), s = t*c;
                double a00 = c*c*A00 - 2.0*s*c*A01 + s*s*A11;
                double a11 = s*s*A00 + 2.0*s*c*A01 + c*c*A11;
                double a02 = c*A02 - s*A12;
                double a12 = s*A02 + c*A12;
                A00 = a00; A11 = a11; A01 = 0.0; A02 = a02; A12 = a12;
                double v0, v1;
                v0 = V00; v1 = V01; V00 = c*v0 - s*v1; V01 = s*v0 + c*v1;
                v0 = V10; v1 = V11; V10 = c*v0 - s*v1; V11 = s*v0 + c*v1;
                v0 = V20; v1 = V21; V20 = c*v0 - s*v1; V21 = s*v0 + c*v1;
            }
        }
        {
            double apq = A02;
            if (fabs(apq) > 1e-300) {
                double th = (A22 - A00) / (2.0*apq);
                double t  = (th >= 0.0 ? 1.0 : -1.0) / (fabs(th) + sqrt(th*th + 1.0));
                double c  = 1.0/sqrt(t*t + 1.0), s = t*c;
                double a00 = c*c*A00 - 2.0*s*c*A02 + s*s*A22;
                double a22 = s*s*A00 + 2.0*s*c*A02 + c*c*A22;
                double a01 = c*A01 - s*A12;
                double a12 = s*A01 + c*A12;
                A00 = a00; A22 = a22; A02 = 0.0; A01 = a01; A12 = a12;
                double v0, v1;
                v0 = V00; v1 = V02; V00 = c*v0 - s*v1; V02 = s*v0 + c*v1;
                v0 = V10; v1 = V12; V10 = c*v0 - s*v1; V12 = s*v0 + c*v1;
                v0 = V20; v1 = V22; V20 = c*v0 - s*v1; V22 = s*v0 + c*v1;
            }
        }
        {
            double apq = A12;
            if (fabs(apq) > 1e-300) {
                double th = (A22 - A11) / (2.0*apq);
                double t  = (th >= 0.0 ? 1.0 : -1.0) / (fabs(th) + sqrt(th*th + 1.0));
                double c  = 1.0/sqrt(t*t + 1.0), s = t*c;
                double a11 = c*c*A11 - 2.0*s*c*A12 + s*s*A22;
                double a22 = s*s*A11 + 2.0*s*c*A12 + c*c*A22;
                double a01 = c*A01 - s*A02;
                double a02 = s*A01 + c*A02;
                A11 = a11; A22 = a22; A12 = 0.0; A01 = a01; A02 = a02;
                double v0, v1;
                v0 = V01; v1 = V02; V01 = c*v0 - s*v1; V02 = s*v0 + c*v1;
                v0 = V11; v1 = V12; V11 = c*v0 - s*v1; V12 = s*v0 + c*v1;
                v0 = V21; v1 = V22; V21 = c*v0 - s*v1; V22 = s*v0 + c*v1;
            }
        }
    }

    double e0 = A00, e1 = A11, e2 = A22;
    double v0, v1, v2;
    if (e0 <= e1 && e0 <= e2)      { v0 = V00; v1 = V10; v2 = V20; }
    else if (e1 <= e0 && e1 <= e2) { v0 = V01; v1 = V11; v2 = V21; }
    else                           { v0 = V02; v1 = V12; v2 = V22; }
    double nrm = sqrt(v0*v0 + v1*v1 + v2*v2);
    if (nrm > 0.0) { v0 /= nrm; v1 /= nrm; v2 /= nrm; }

    float f0 = (float)v0, f1 = (float)v1, f2 = (float)v2;
    float proj = f0*S0 + f1*S1 + f2*S2;
    if (proj < 0.0f) { f0 = -f0; f1 = -f1; f2 = -f2; }
    normals[(size_t)pid*3+0] = f0;
    normals[(size_t)pid*3+1] = f1;
    normals[(size_t)pid*3+2] = f2;
}

// ---------------- Pass 2: penalty std + batch mean ----------------
__global__ __launch_bounds__(64) void penalty_kernel(
        const float* __restrict__ normals,
        const int*   __restrict__ idx8,
        float*       __restrict__ out)
{
    const int pid = blockIdx.x * 64 + threadIdx.x;    // < B*N
    const int b   = pid >> 12;
    const int* my = idx8 + (size_t)pid * KSUP;
    const float* nb_base = normals + (size_t)b * NPTS * 3;

    const int i0 = my[0];
    const float a0 = nb_base[i0*3+0], a1 = nb_base[i0*3+1], a2 = nb_base[i0*3+2];
    const float na = fmaxf(sqrtf(a0*a0 + a1*a1 + a2*a2), 1e-6f);

    float p[KSUP];
    float sum = 0.0f;
    #pragma unroll
    for (int k = 0; k < KSUP; ++k) {
        int ik = my[k];
        float b0 = nb_base[ik*3+0], b1 = nb_base[ik*3+1], b2 = nb_base[ik*3+2];
        float nbn = fmaxf(sqrtf(b0*b0 + b1*b1 + b2*b2), 1e-6f);
        float cosv = (a0*b0 + a1*b1 + a2*b2) / (na * nbn);
        p[k] = 1.0f - cosv;
        sum += p[k];
    }
    const float mean = sum * (1.0f / 8.0f);
    float var = 0.0f;
    #pragma unroll
    for (int k = 0; k < KSUP; ++k) { float dv = p[k] - mean; var += dv * dv; }
    float v = sqrtf(var * (1.0f / 7.0f)) * (1.0f / 4096.0f);

    #pragma unroll
    for (int ml = 1; ml < 64; ml <<= 1) v += __shfl_xor(v, ml, 64);
    if (threadIdx.x == 0) atomicAdd(&out[b], v);
}

extern "C" void kernel_launch(void* const* d_in, const int* in_sizes, int n_in,
                              void* d_out, int out_size, void* d_ws, size_t ws_size,
                              hipStream_t stream) {
    const float* xyz = (const float*)d_in[0];
    float* out = (float*)d_out;

    const int B = in_sizes[0] / (NPTS * 3);   // 4
    const int total = B * NPTS;

    char* ws = (char*)d_ws;
    float4* pts4   = (float4*)ws;                       ws += (size_t)total * sizeof(float4);
    float*  covS   = (float*)ws;                        ws += (size_t)total * 12 * sizeof(float);
    float*  normals= (float*)ws;                        ws += (size_t)total * 3 * sizeof(float);
    int*    idx8   = (int*)ws;

    hipLaunchKernelGGL(pack_kernel, dim3((total + 63) / 64), dim3(64), 0, stream,
                       xyz, pts4, total, out, out_size);
    hipLaunchKernelGGL(knn_cov_kernel, dim3(total / QPB), dim3(256), 0, stream,
                       pts4, covS, idx8);
    hipLaunchKernelGGL(eig_kernel, dim3((total + 63) / 64), dim3(64), 0, stream,
                       covS, normals, total);
    hipLaunchKernelGGL(penalty_kernel, dim3(total / 64), dim3(64), 0, stream,
                       normals, idx8, out);
}